// Round 1
// baseline (599.764 us; speedup 1.0000x reference)
//
#include <hip/hip_runtime.h>

// EMA Vector-Quantizer for MI355X (gfx950).
// N=16384 tokens (16 x 32 x 32), D=64, K=8192 codes.
// Dominant cost: 16384x8192x64 fp32 GEMM for the distance argmin (no fp32 MFMA
// on CDNA4 -> vector ALU, ~110us floor at 157 TF).

#define N_TOK 16384
#define K_EMB 8192
#define EMB_D 64
#define TN 128
#define TK 128
#define GROUPS 4
#define KPG (K_EMB / GROUPS)   // 2048 codes per k-group

// d_out flat layout (float32), in reference return order:
// z_q (16,64,32,32) | loss | new_weight (8192,64) | new_cluster_size (8192) | new_embed_avg (8192,64)
#define OFF_LOSS 1048576
#define OFF_W    1048577
#define OFF_CS   1572865
#define OFF_EA   1581057

// ws float offsets
#define WS_NSUM  0
#define WS_LOSS  1
#define WS_WNORM 16
#define WS_CD    (WS_WNORM + K_EMB)           // cand dist  [GROUPS][N_TOK]
#define WS_CI    (WS_CD + GROUPS * N_TOK)     // cand idx   [GROUPS][N_TOK]
#define WS_IDX   (WS_CI + GROUPS * N_TOK)     // final idx  [N_TOK]

// ---------------------------------------------------------------------------
// K0: wnorm[k] = sum_d weight[k][d]^2 ; zero the in-place accumulator regions.
// grid 512 x 256 (131072 threads): 16 lanes per codebook row.
__global__ void k_prep(const float* __restrict__ weight,
                       float* __restrict__ out, float* __restrict__ ws) {
  int gid = blockIdx.x * 256 + threadIdx.x;     // 0..131071
  int row = gid >> 4;
  int l16 = gid & 15;
  float4 w4 = *(const float4*)(weight + row * EMB_D + l16 * 4);
  float s = w4.x * w4.x + w4.y * w4.y + w4.z * w4.z + w4.w * w4.w;
  #pragma unroll
  for (int off = 8; off > 0; off >>= 1) s += __shfl_xor(s, off, 16);
  if (l16 == 0) ws[WS_WNORM + row] = s;

  // zero embed_sum accumulator (524288 elems; OFF_EA is odd -> scalar stores)
  #pragma unroll
  for (int j = 0; j < 4; ++j) out[OFF_EA + gid * 4 + j] = 0.f;
  if (gid < K_EMB) out[OFF_CS + gid] = 0.f;
  if (gid == 0) { out[OFF_LOSS] = 0.f; ws[WS_NSUM] = 0.f; ws[WS_LOSS] = 0.f; }
}

// ---------------------------------------------------------------------------
// K1: distance argmin. Block tile 128n x 128k; 16x16 threads, 8x8 regs each.
// grid (128 n-tiles, 4 k-groups) x 256. LDS 66KB -> 2 blocks/CU, 8 waves/CU.
__global__ __launch_bounds__(256, 2) void k_argmin(
    const float* __restrict__ z, const float* __restrict__ weight,
    const float* __restrict__ wnorm, float* __restrict__ cd,
    int* __restrict__ ci) {
  __shared__ __align__(16) float z_s[EMB_D * TN];  // [d][n]
  __shared__ __align__(16) float w_s[EMB_D * TK];  // [d][k]
  __shared__ float wn_s[TK];
  const int t = threadIdx.x;
  const int n0 = blockIdx.x * TN;
  const int kbase = blockIdx.y * KPG;
  // z is (b, c, hw): z_flat[n][d] = z[b*65536 + d*1024 + hw], n = b*1024+hw.
  const float* zb = z + ((n0 >> 10) << 16) + (n0 & 1023);

  // Load z tile once: 64 rows (d) x 128 floats (n), contiguous per row.
  #pragma unroll
  for (int i = 0; i < 8; ++i) {
    int f4 = i * 256 + t;                 // 0..2047 float4s
    int d = f4 >> 5, c4 = (f4 & 31) * 4;
    *(float4*)(z_s + d * TN + c4) = *(const float4*)(zb + d * 1024 + c4);
  }

  const int tx = t & 15, ty = t >> 4;     // tx -> k, ty -> n
  float bestd[8];
  int besti[8];
  #pragma unroll
  for (int i = 0; i < 8; ++i) { bestd[i] = 3.4e38f; besti[i] = 0; }

  for (int kt = 0; kt < KPG / TK; ++kt) {
    const int ktb = kbase + kt * TK;
    __syncthreads();
    // Load w tile transposed: global [k][d] -> LDS [d][k].
    #pragma unroll
    for (int i = 0; i < 8; ++i) {
      int f4 = i * 256 + t;
      int kl = f4 >> 4, d4 = (f4 & 15) * 4;
      float4 v = *(const float4*)(weight + (ktb + kl) * EMB_D + d4);
      w_s[(d4 + 0) * TK + kl] = v.x;
      w_s[(d4 + 1) * TK + kl] = v.y;
      w_s[(d4 + 2) * TK + kl] = v.z;
      w_s[(d4 + 3) * TK + kl] = v.w;
    }
    if (t < TK) wn_s[t] = wnorm[ktb + t];
    __syncthreads();

    float acc[8][8];
    #pragma unroll
    for (int i = 0; i < 8; ++i)
      #pragma unroll
      for (int j = 0; j < 8; ++j) acc[i][j] = 0.f;

    #pragma unroll 4
    for (int d = 0; d < EMB_D; ++d) {
      float4 za = *(const float4*)(z_s + d * TN + ty * 8);
      float4 zc = *(const float4*)(z_s + d * TN + ty * 8 + 4);
      float4 wa = *(const float4*)(w_s + d * TK + tx * 8);
      float4 wb = *(const float4*)(w_s + d * TK + tx * 8 + 4);
      float zr[8] = {za.x, za.y, za.z, za.w, zc.x, zc.y, zc.z, zc.w};
      float wr[8] = {wa.x, wa.y, wa.z, wa.w, wb.x, wb.y, wb.z, wb.w};
      #pragma unroll
      for (int i = 0; i < 8; ++i)
        #pragma unroll
        for (int j = 0; j < 8; ++j)
          acc[i][j] = fmaf(zr[i], wr[j], acc[i][j]);
    }

    // dist = |w|^2 - 2*dot (|z|^2 constant per n -> same argmin).
    // Strict < with k ascending == numpy argmin first-min tie-break.
    #pragma unroll
    for (int j = 0; j < 8; ++j) {
      float wn = wn_s[tx * 8 + j];
      int kg = ktb + tx * 8 + j;
      #pragma unroll
      for (int i = 0; i < 8; ++i) {
        float dist = fmaf(-2.f, acc[i][j], wn);
        if (dist < bestd[i]) { bestd[i] = dist; besti[i] = kg; }
      }
    }
  }

  // Reduce across the 16 tx threads sharing each n (same wave, width 16).
  #pragma unroll
  for (int i = 0; i < 8; ++i) {
    float bd = bestd[i]; int bi = besti[i];
    #pragma unroll
    for (int off = 8; off > 0; off >>= 1) {
      float od = __shfl_xor(bd, off, 16);
      int oi = __shfl_xor(bi, off, 16);
      if (od < bd || (od == bd && oi < bi)) { bd = od; bi = oi; }
    }
    if (tx == 0) {
      int n = n0 + ty * 8 + i;
      cd[blockIdx.y * N_TOK + n] = bd;
      ci[blockIdx.y * N_TOK + n] = bi;
    }
  }
}

// ---------------------------------------------------------------------------
// K2: reduce the GROUPS candidates per token; enc_sum atomics.
// Groups cover ascending k-ranges, so strict < keeps the smallest index on tie.
__global__ void k_reduce(const float* __restrict__ cd, const int* __restrict__ ci,
                         int* __restrict__ idx, float* __restrict__ enc) {
  int n = blockIdx.x * 256 + threadIdx.x;
  float bd = cd[n]; int bi = ci[n];
  #pragma unroll
  for (int g = 1; g < GROUPS; ++g) {
    float od = cd[g * N_TOK + n];
    int oi = ci[g * N_TOK + n];
    if (od < bd) { bd = od; bi = oi; }
  }
  idx[n] = bi;
  atomicAdd(enc + bi, 1.0f);
}

// ---------------------------------------------------------------------------
// K3: z_q gather + straight-through output + loss partials + embed_sum atomics.
// grid 1024 x 256, 4 elems/thread (stride-256 for coalescing).
__global__ void k_quant(const float* __restrict__ z, const float* __restrict__ weight,
                        const int* __restrict__ idx, float* __restrict__ out,
                        float* __restrict__ embed_acc, float* __restrict__ ws) {
  int base = blockIdx.x * 1024 + threadIdx.x;
  float lsum = 0.f;
  #pragma unroll
  for (int i = 0; i < 4; ++i) {
    int e = base + i * 256;               // (b,c,hw) flat, same layout as z
    int c = (e >> 10) & 63;
    int n = ((e >> 16) << 10) | (e & 1023);
    int k = idx[n];
    float zv = z[e];
    float q = weight[k * EMB_D + c];
    out[e] = zv + (q - zv);               // straight-through value
    float d = q - zv;
    lsum += d * d;
    atomicAdd(embed_acc + k * EMB_D + c, zv);
  }
  #pragma unroll
  for (int off = 32; off > 0; off >>= 1) lsum += __shfl_xor(lsum, off, 64);
  __shared__ float red[4];
  int lane = threadIdx.x & 63, wv = threadIdx.x >> 6;
  if (lane == 0) red[wv] = lsum;
  __syncthreads();
  if (threadIdx.x == 0)
    atomicAdd(ws + WS_LOSS, red[0] + red[1] + red[2] + red[3]);
}

// ---------------------------------------------------------------------------
// K4: new_cluster_size (in place over enc_sum), n-sum, loss finalize.
__global__ void k_cluster(const float* __restrict__ cluster_in,
                          float* __restrict__ out, float* __restrict__ ws) {
  int k = blockIdx.x * 256 + threadIdx.x;
  float ncs = cluster_in[k] * 0.99f + 0.01f * out[OFF_CS + k];
  out[OFF_CS + k] = ncs;
  float s = ncs;
  #pragma unroll
  for (int off = 32; off > 0; off >>= 1) s += __shfl_xor(s, off, 64);
  __shared__ float red[4];
  int lane = threadIdx.x & 63, wv = threadIdx.x >> 6;
  if (lane == 0) red[wv] = s;
  __syncthreads();
  if (threadIdx.x == 0) atomicAdd(ws + WS_NSUM, red[0] + red[1] + red[2] + red[3]);
  if (blockIdx.x == 0 && threadIdx.x == 0)
    out[OFF_LOSS] = 0.25f * ws[WS_LOSS] * (1.0f / 1048576.0f);
}

// ---------------------------------------------------------------------------
// K5: smoothed cluster sizes -> new_weight; new_embed_avg (in place).
__global__ void k_final(const float* __restrict__ embed_avg,
                        float* __restrict__ out, const float* __restrict__ ws) {
  int e = blockIdx.x * 256 + threadIdx.x;   // < 524288
  int k = e >> 6;
  float ncs = out[OFF_CS + k];
  float nsum = ws[WS_NSUM];
  float sm = (ncs + 1e-5f) / (nsum + K_EMB * 1e-5f) * nsum;
  float ea = embed_avg[e] * 0.99f + 0.01f * out[OFF_EA + e];
  out[OFF_EA + e] = ea;
  out[OFF_W + e] = ea / sm;
}

// ---------------------------------------------------------------------------
extern "C" void kernel_launch(void* const* d_in, const int* in_sizes, int n_in,
                              void* d_out, int out_size, void* d_ws, size_t ws_size,
                              hipStream_t stream) {
  const float* z = (const float*)d_in[0];
  const float* weight = (const float*)d_in[1];
  const float* cluster = (const float*)d_in[2];
  const float* embed_avg = (const float*)d_in[3];
  float* out = (float*)d_out;
  float* ws = (float*)d_ws;   // needs ~623 KB
  float* wnorm = ws + WS_WNORM;
  float* cd = ws + WS_CD;
  int* ci = (int*)(ws + WS_CI);
  int* idx = (int*)(ws + WS_IDX);

  hipLaunchKernelGGL(k_prep, dim3(512), dim3(256), 0, stream, weight, out, ws);
  hipLaunchKernelGGL(k_argmin, dim3(N_TOK / TN, GROUPS), dim3(256), 0, stream,
                     z, weight, wnorm, cd, ci);
  hipLaunchKernelGGL(k_reduce, dim3(N_TOK / 256), dim3(256), 0, stream,
                     cd, ci, idx, out + OFF_CS);
  hipLaunchKernelGGL(k_quant, dim3(1024), dim3(256), 0, stream,
                     z, weight, idx, out, out + OFF_EA, ws);
  hipLaunchKernelGGL(k_cluster, dim3(K_EMB / 256), dim3(256), 0, stream,
                     cluster, out, ws);
  hipLaunchKernelGGL(k_final, dim3(524288 / 256), dim3(256), 0, stream,
                     embed_avg, out, ws);
}

// Round 2
// 471.440 us; speedup vs baseline: 1.2722x; 1.2722x over previous
//
#include <hip/hip_runtime.h>

// EMA Vector-Quantizer for MI355X (gfx950).
// N=16384 tokens (16 x 32 x 32), D=64, K=8192 codes.
// Dominant cost: 16384x8192x64 fp32 GEMM for the distance argmin (no fp32 MFMA
// on CDNA4 -> vector ALU, ~110us floor at 157 TF).
// R1: fix LDS bank conflicts (1.6e8 conflict cycles in R0):
//  - w inner-loop reads: k = g*64 + tx*4 (contig 64-float span, 2-way = free)
//  - w transpose stores: lane-major kl (2-way distinct = free)
//  - register-prefetch next w tile across the compute phase

#define N_TOK 16384
#define K_EMB 8192
#define EMB_D 64
#define TN 128
#define TK 128
#define GROUPS 4
#define KPG (K_EMB / GROUPS)   // 2048 codes per k-group

// d_out flat layout (float32), in reference return order:
// z_q (16,64,32,32) | loss | new_weight (8192,64) | new_cluster_size (8192) | new_embed_avg (8192,64)
#define OFF_LOSS 1048576
#define OFF_W    1048577
#define OFF_CS   1572865
#define OFF_EA   1581057

// ws float offsets
#define WS_NSUM  0
#define WS_LOSS  1
#define WS_WNORM 16
#define WS_CD    (WS_WNORM + K_EMB)           // cand dist  [GROUPS][N_TOK]
#define WS_CI    (WS_CD + GROUPS * N_TOK)     // cand idx   [GROUPS][N_TOK]
#define WS_IDX   (WS_CI + GROUPS * N_TOK)     // final idx  [N_TOK]

// ---------------------------------------------------------------------------
// K0: wnorm[k] = sum_d weight[k][d]^2 ; zero the in-place accumulator regions.
__global__ void k_prep(const float* __restrict__ weight,
                       float* __restrict__ out, float* __restrict__ ws) {
  int gid = blockIdx.x * 256 + threadIdx.x;     // 0..131071
  int row = gid >> 4;
  int l16 = gid & 15;
  float4 w4 = *(const float4*)(weight + row * EMB_D + l16 * 4);
  float s = w4.x * w4.x + w4.y * w4.y + w4.z * w4.z + w4.w * w4.w;
  #pragma unroll
  for (int off = 8; off > 0; off >>= 1) s += __shfl_xor(s, off, 16);
  if (l16 == 0) ws[WS_WNORM + row] = s;

  #pragma unroll
  for (int j = 0; j < 4; ++j) out[OFF_EA + gid * 4 + j] = 0.f;
  if (gid < K_EMB) out[OFF_CS + gid] = 0.f;
  if (gid == 0) { out[OFF_LOSS] = 0.f; ws[WS_NSUM] = 0.f; ws[WS_LOSS] = 0.f; }
}

// ---------------------------------------------------------------------------
// K1: distance argmin. Block tile 128n x 128k; 16x16 threads, 8x8 regs each.
// grid (128 n-tiles, 4 k-groups) x 256. LDS 66KB -> 2 blocks/CU, 8 waves/CU.
// Thread k-fragment: k = g*64 + tx*4 + j (g in {0,1}, j in 0..3) so that each
// w read is 16 lanes x float4 over a contiguous 64-float span (bank-clean).
__global__ __launch_bounds__(256, 2) void k_argmin(
    const float* __restrict__ z, const float* __restrict__ weight,
    const float* __restrict__ wnorm, float* __restrict__ cd,
    int* __restrict__ ci) {
  __shared__ __align__(16) float z_s[EMB_D * TN];  // [d][n]
  __shared__ __align__(16) float w_s[EMB_D * TK];  // [d][k]
  __shared__ float wn_s[TK];
  const int t = threadIdx.x;
  const int n0 = blockIdx.x * TN;
  const int kbase = blockIdx.y * KPG;
  // z is (b, c, hw): z_flat[n][d] = z[b*65536 + d*1024 + hw], n = b*1024+hw.
  const float* zb = z + ((n0 >> 10) << 16) + (n0 & 1023);

  // Load z tile once: 64 rows (d) x 128 floats (n), contiguous per row.
  #pragma unroll
  for (int i = 0; i < 8; ++i) {
    int f4 = i * 256 + t;                 // 0..2047 float4s
    int d = f4 >> 5, c4 = (f4 & 31) * 4;
    *(float4*)(z_s + d * TN + c4) = *(const float4*)(zb + d * 1024 + c4);
  }

  // w tile staging indices (lane-major kl so ds stores are 2-way/free).
  const int kl = t & 127;                 // k within tile (0..127)
  const int dg0 = (t >> 7) * 4;           // this thread covers dg0, dg0+8*? ...
  // Each thread loads 8 float4s: (kl, dg) for dg = dg0.. step 8 -> wait:
  // id = i*256 + t -> kl = id & 127, dg = id >> 7 = i*2 + (t>>7).
  float4 pre[8];
  #pragma unroll
  for (int i = 0; i < 8; ++i) {
    int dg = i * 2 + (t >> 7);
    pre[i] = *(const float4*)(weight + (kbase + kl) * EMB_D + dg * 4);
  }

  const int tx = t & 15, ty = t >> 4;     // tx -> k groups, ty -> n
  float bestd[8];
  int besti[8];
  #pragma unroll
  for (int i = 0; i < 8; ++i) { bestd[i] = 3.4e38f; besti[i] = 0; }

  for (int kt = 0; kt < KPG / TK; ++kt) {
    const int ktb = kbase + kt * TK;
    __syncthreads();
    // Transposed store: [d][k], lanes are kl-major -> consecutive addresses.
    #pragma unroll
    for (int i = 0; i < 8; ++i) {
      int dg = i * 2 + (t >> 7);
      w_s[(dg * 4 + 0) * TK + kl] = pre[i].x;
      w_s[(dg * 4 + 1) * TK + kl] = pre[i].y;
      w_s[(dg * 4 + 2) * TK + kl] = pre[i].z;
      w_s[(dg * 4 + 3) * TK + kl] = pre[i].w;
    }
    if (t < TK) wn_s[t] = wnorm[ktb + t];
    // Prefetch next tile while this tile computes.
    if (kt + 1 < KPG / TK) {
      #pragma unroll
      for (int i = 0; i < 8; ++i) {
        int dg = i * 2 + (t >> 7);
        pre[i] = *(const float4*)(weight + (ktb + TK + kl) * EMB_D + dg * 4);
      }
    }
    __syncthreads();

    float acc[8][8];
    #pragma unroll
    for (int i = 0; i < 8; ++i)
      #pragma unroll
      for (int j = 0; j < 8; ++j) acc[i][j] = 0.f;

    #pragma unroll 4
    for (int d = 0; d < EMB_D; ++d) {
      float4 za = *(const float4*)(z_s + d * TN + ty * 8);
      float4 zc = *(const float4*)(z_s + d * TN + ty * 8 + 4);
      float4 wa = *(const float4*)(w_s + d * TK + tx * 4);        // g=0
      float4 wb = *(const float4*)(w_s + d * TK + 64 + tx * 4);   // g=1
      float zr[8] = {za.x, za.y, za.z, za.w, zc.x, zc.y, zc.z, zc.w};
      float wr[8] = {wa.x, wa.y, wa.z, wa.w, wb.x, wb.y, wb.z, wb.w};
      #pragma unroll
      for (int i = 0; i < 8; ++i)
        #pragma unroll
        for (int j = 0; j < 8; ++j)
          acc[i][j] = fmaf(zr[i], wr[j], acc[i][j]);
    }

    // dist = |w|^2 - 2*dot. Per-thread k ascends over (g, j) -> strict <
    // keeps first-min; cross-thread ties resolved by index compare below.
    #pragma unroll
    for (int g = 0; g < 2; ++g)
      #pragma unroll
      for (int j = 0; j < 4; ++j) {
        int kk = g * 64 + tx * 4 + j;
        float wn = wn_s[kk];
        int kg = ktb + kk;
        #pragma unroll
        for (int i = 0; i < 8; ++i) {
          float dist = fmaf(-2.f, acc[i][g * 4 + j], wn);
          if (dist < bestd[i]) { bestd[i] = dist; besti[i] = kg; }
        }
      }
  }

  // Reduce across the 16 tx threads sharing each n (same wave, width 16).
  #pragma unroll
  for (int i = 0; i < 8; ++i) {
    float bd = bestd[i]; int bi = besti[i];
    #pragma unroll
    for (int off = 8; off > 0; off >>= 1) {
      float od = __shfl_xor(bd, off, 16);
      int oi = __shfl_xor(bi, off, 16);
      if (od < bd || (od == bd && oi < bi)) { bd = od; bi = oi; }
    }
    if (tx == 0) {
      int n = n0 + ty * 8 + i;
      cd[blockIdx.y * N_TOK + n] = bd;
      ci[blockIdx.y * N_TOK + n] = bi;
    }
  }
}

// ---------------------------------------------------------------------------
// K2: reduce the GROUPS candidates per token; enc_sum atomics.
__global__ void k_reduce(const float* __restrict__ cd, const int* __restrict__ ci,
                         int* __restrict__ idx, float* __restrict__ enc) {
  int n = blockIdx.x * 256 + threadIdx.x;
  float bd = cd[n]; int bi = ci[n];
  #pragma unroll
  for (int g = 1; g < GROUPS; ++g) {
    float od = cd[g * N_TOK + n];
    int oi = ci[g * N_TOK + n];
    if (od < bd) { bd = od; bi = oi; }
  }
  idx[n] = bi;
  atomicAdd(enc + bi, 1.0f);
}

// ---------------------------------------------------------------------------
// K3: z_q gather + straight-through output + loss partials + embed_sum atomics.
__global__ void k_quant(const float* __restrict__ z, const float* __restrict__ weight,
                        const int* __restrict__ idx, float* __restrict__ out,
                        float* __restrict__ embed_acc, float* __restrict__ ws) {
  int base = blockIdx.x * 1024 + threadIdx.x;
  float lsum = 0.f;
  #pragma unroll
  for (int i = 0; i < 4; ++i) {
    int e = base + i * 256;               // (b,c,hw) flat, same layout as z
    int c = (e >> 10) & 63;
    int n = ((e >> 16) << 10) | (e & 1023);
    int k = idx[n];
    float zv = z[e];
    float q = weight[k * EMB_D + c];
    out[e] = zv + (q - zv);               // straight-through value
    float d = q - zv;
    lsum += d * d;
    atomicAdd(embed_acc + k * EMB_D + c, zv);
  }
  #pragma unroll
  for (int off = 32; off > 0; off >>= 1) lsum += __shfl_xor(lsum, off, 64);
  __shared__ float red[4];
  int lane = threadIdx.x & 63, wv = threadIdx.x >> 6;
  if (lane == 0) red[wv] = lsum;
  __syncthreads();
  if (threadIdx.x == 0)
    atomicAdd(ws + WS_LOSS, red[0] + red[1] + red[2] + red[3]);
}

// ---------------------------------------------------------------------------
// K4: new_cluster_size (in place over enc_sum), n-sum, loss finalize.
__global__ void k_cluster(const float* __restrict__ cluster_in,
                          float* __restrict__ out, float* __restrict__ ws) {
  int k = blockIdx.x * 256 + threadIdx.x;
  float ncs = cluster_in[k] * 0.99f + 0.01f * out[OFF_CS + k];
  out[OFF_CS + k] = ncs;
  float s = ncs;
  #pragma unroll
  for (int off = 32; off > 0; off >>= 1) s += __shfl_xor(s, off, 64);
  __shared__ float red[4];
  int lane = threadIdx.x & 63, wv = threadIdx.x >> 6;
  if (lane == 0) red[wv] = s;
  __syncthreads();
  if (threadIdx.x == 0) atomicAdd(ws + WS_NSUM, red[0] + red[1] + red[2] + red[3]);
  if (blockIdx.x == 0 && threadIdx.x == 0)
    out[OFF_LOSS] = 0.25f * ws[WS_LOSS] * (1.0f / 1048576.0f);
}

// ---------------------------------------------------------------------------
// K5: smoothed cluster sizes -> new_weight; new_embed_avg (in place).
__global__ void k_final(const float* __restrict__ embed_avg,
                        float* __restrict__ out, const float* __restrict__ ws) {
  int e = blockIdx.x * 256 + threadIdx.x;   // < 524288
  int k = e >> 6;
  float ncs = out[OFF_CS + k];
  float nsum = ws[WS_NSUM];
  float sm = (ncs + 1e-5f) / (nsum + K_EMB * 1e-5f) * nsum;
  float ea = embed_avg[e] * 0.99f + 0.01f * out[OFF_EA + e];
  out[OFF_EA + e] = ea;
  out[OFF_W + e] = ea / sm;
}

// ---------------------------------------------------------------------------
extern "C" void kernel_launch(void* const* d_in, const int* in_sizes, int n_in,
                              void* d_out, int out_size, void* d_ws, size_t ws_size,
                              hipStream_t stream) {
  const float* z = (const float*)d_in[0];
  const float* weight = (const float*)d_in[1];
  const float* cluster = (const float*)d_in[2];
  const float* embed_avg = (const float*)d_in[3];
  float* out = (float*)d_out;
  float* ws = (float*)d_ws;   // needs ~623 KB
  float* wnorm = ws + WS_WNORM;
  float* cd = ws + WS_CD;
  int* ci = (int*)(ws + WS_CI);
  int* idx = (int*)(ws + WS_IDX);

  hipLaunchKernelGGL(k_prep, dim3(512), dim3(256), 0, stream, weight, out, ws);
  hipLaunchKernelGGL(k_argmin, dim3(N_TOK / TN, GROUPS), dim3(256), 0, stream,
                     z, weight, wnorm, cd, ci);
  hipLaunchKernelGGL(k_reduce, dim3(N_TOK / 256), dim3(256), 0, stream,
                     cd, ci, idx, out + OFF_CS);
  hipLaunchKernelGGL(k_quant, dim3(1024), dim3(256), 0, stream,
                     z, weight, idx, out, out + OFF_EA, ws);
  hipLaunchKernelGGL(k_cluster, dim3(K_EMB / 256), dim3(256), 0, stream,
                     cluster, out, ws);
  hipLaunchKernelGGL(k_final, dim3(524288 / 256), dim3(256), 0, stream,
                     embed_avg, out, ws);
}

// Round 3
// 461.331 us; speedup vs baseline: 1.3001x; 1.0219x over previous
//
#include <hip/hip_runtime.h>

// EMA Vector-Quantizer for MI355X (gfx950).
// N=16384 tokens, D=64, K=8192. Dominant cost: 16384x8192x64 fp32 GEMM for
// distance argmin (no fp32 MFMA on CDNA4 -> VALU, 109 us FMA floor).
// R3: w NOT in LDS. Pre-transposed w_t[d][k] read straight from global
// (L1/L2-resident, contiguous dwordx4); LDS holds only z (broadcast reads);
// no K-loop barriers; GROUPS=8 -> 4 blocks/CU = 16 waves/CU (4/SIMD).
// Scratch (w_t, candidate dist/idx) lives in the z_q region of d_out, which
// k_quant fully overwrites afterwards.

#define N_TOK 16384
#define K_EMB 8192
#define EMB_D 64
#define TN 128
#define GROUPS 8
#define KPG (K_EMB / GROUPS)   // 1024 codes per k-group, 8 kb-tiles of 128

// d_out flat layout (float32), in reference return order:
// z_q (1048576) | loss | new_weight (524288) | new_cluster_size (8192) | new_embed_avg (524288)
#define OFF_LOSS 1048576
#define OFF_W    1048577
#define OFF_CS   1572865
#define OFF_EA   1581057

// scratch inside the z_q region of out (all < 1048576, overwritten by k_quant)
#define OUT_WT 0                        // w_t[d][k]: 64 x 8192 = 524288 floats
#define OUT_CD 524288                   // cand dist [GROUPS][N_TOK] = 131072
#define OUT_CI (524288 + 131072)        // cand idx  [GROUPS][N_TOK] = 131072

// ws float offsets
#define WS_NSUM  0
#define WS_LOSS  1
#define WS_WNORM 16
#define WS_IDX   (WS_WNORM + K_EMB)

// ---------------------------------------------------------------------------
// K0: wnorm[k]; transpose weight -> w_t[d][k] (in out); zero accumulators.
__global__ void k_prep(const float* __restrict__ weight,
                       float* __restrict__ out, float* __restrict__ ws) {
  int gid = blockIdx.x * 256 + threadIdx.x;     // 0..131071
  int row = gid >> 4;                            // codebook row 0..8191
  int l16 = gid & 15;
  float4 w4 = *(const float4*)(weight + row * EMB_D + l16 * 4);
  float s = w4.x * w4.x + w4.y * w4.y + w4.z * w4.z + w4.w * w4.w;
  #pragma unroll
  for (int off = 8; off > 0; off >>= 1) s += __shfl_xor(s, off, 16);
  if (l16 == 0) ws[WS_WNORM + row] = s;

  // transposed copy: w_t[(d)*8192 + row], d = l16*4+c
  out[OUT_WT + (l16 * 4 + 0) * K_EMB + row] = w4.x;
  out[OUT_WT + (l16 * 4 + 1) * K_EMB + row] = w4.y;
  out[OUT_WT + (l16 * 4 + 2) * K_EMB + row] = w4.z;
  out[OUT_WT + (l16 * 4 + 3) * K_EMB + row] = w4.w;

  #pragma unroll
  for (int j = 0; j < 4; ++j) out[OFF_EA + gid * 4 + j] = 0.f;
  if (gid < K_EMB) out[OFF_CS + gid] = 0.f;
  if (gid == 0) { out[OFF_LOSS] = 0.f; ws[WS_NSUM] = 0.f; ws[WS_LOSS] = 0.f; }
}

// ---------------------------------------------------------------------------
// K1: distance argmin. Block: 128 n x 1024 k; thread tile 8n x 8k.
// grid (128, 8) x 256 threads. LDS 32KB -> 4 blocks/CU, 16 waves/CU.
// w fragment: k = ktb + g*64 + tx*4 + j -> contiguous dwordx4 from w_t rows.
// z fragment: LDS broadcast (16 lanes share each address).
__global__ __launch_bounds__(256, 4) void k_argmin(
    const float* __restrict__ z, const float* __restrict__ wt,
    const float* __restrict__ wnorm, float* __restrict__ cd,
    int* __restrict__ ci) {
  __shared__ __align__(16) float z_s[EMB_D * TN];  // [d][n], 32 KB
  const int t = threadIdx.x;
  const int n0 = blockIdx.x * TN;
  const int kbase = blockIdx.y * KPG;
  // z is (b, c, hw): z_flat[n][d] = z[b*65536 + d*1024 + hw], n = b*1024+hw.
  const float* zb = z + ((n0 >> 10) << 16) + (n0 & 1023);

  #pragma unroll
  for (int i = 0; i < 8; ++i) {
    int f4 = i * 256 + t;                 // 0..2047 float4s
    int d = f4 >> 5, c4 = (f4 & 31) * 4;
    *(float4*)(z_s + d * TN + c4) = *(const float4*)(zb + d * 1024 + c4);
  }
  __syncthreads();                        // the only barrier

  const int tx = t & 15, ty = t >> 4;     // tx -> k, ty -> n
  float bestd[8];
  int besti[8];
  #pragma unroll
  for (int i = 0; i < 8; ++i) { bestd[i] = 3.4e38f; besti[i] = 0; }

  for (int kb = 0; kb < KPG / 128; ++kb) {
    const int ktb = kbase + kb * 128;
    float4 wn0 = *(const float4*)(wnorm + ktb + tx * 4);
    float4 wn1 = *(const float4*)(wnorm + ktb + 64 + tx * 4);

    float acc[8][8];
    #pragma unroll
    for (int i = 0; i < 8; ++i)
      #pragma unroll
      for (int j = 0; j < 8; ++j) acc[i][j] = 0.f;

    const float* wp = wt + ktb + tx * 4;  // row stride K_EMB per d
    #pragma unroll 4
    for (int d = 0; d < EMB_D; ++d) {
      float4 z0 = *(const float4*)(z_s + d * TN + ty * 8);
      float4 z1 = *(const float4*)(z_s + d * TN + ty * 8 + 4);
      float4 w0 = *(const float4*)(wp);
      float4 w1 = *(const float4*)(wp + 64);
      wp += K_EMB;
      float zr[8] = {z0.x, z0.y, z0.z, z0.w, z1.x, z1.y, z1.z, z1.w};
      float wr[8] = {w0.x, w0.y, w0.z, w0.w, w1.x, w1.y, w1.z, w1.w};
      #pragma unroll
      for (int i = 0; i < 8; ++i)
        #pragma unroll
        for (int j = 0; j < 8; ++j)
          acc[i][j] = fmaf(zr[i], wr[j], acc[i][j]);
    }

    // dist = |w|^2 - 2*dot. Per-thread k ascends over (g, j) -> strict <
    // keeps first-min; cross-thread ties resolved by index compare below.
    float wna[8] = {wn0.x, wn0.y, wn0.z, wn0.w, wn1.x, wn1.y, wn1.z, wn1.w};
    #pragma unroll
    for (int g = 0; g < 2; ++g)
      #pragma unroll
      for (int j = 0; j < 4; ++j) {
        int col = g * 4 + j;
        int kg = ktb + g * 64 + tx * 4 + j;
        float wn = wna[col];
        #pragma unroll
        for (int i = 0; i < 8; ++i) {
          float dist = fmaf(-2.f, acc[i][col], wn);
          if (dist < bestd[i]) { bestd[i] = dist; besti[i] = kg; }
        }
      }
  }

  // Reduce across the 16 tx threads sharing each n (same wave, width 16).
  #pragma unroll
  for (int i = 0; i < 8; ++i) {
    float bd = bestd[i]; int bi = besti[i];
    #pragma unroll
    for (int off = 8; off > 0; off >>= 1) {
      float od = __shfl_xor(bd, off, 16);
      int oi = __shfl_xor(bi, off, 16);
      if (od < bd || (od == bd && oi < bi)) { bd = od; bi = oi; }
    }
    if (tx == 0) {
      int n = n0 + ty * 8 + i;
      cd[blockIdx.y * N_TOK + n] = bd;
      ci[blockIdx.y * N_TOK + n] = bi;
    }
  }
}

// ---------------------------------------------------------------------------
// K2: reduce the GROUPS candidates per token; enc_sum atomics.
// Groups cover ascending k-ranges, so strict < keeps smallest index on tie.
__global__ void k_reduce(const float* __restrict__ cd, const int* __restrict__ ci,
                         int* __restrict__ idx, float* __restrict__ enc) {
  int n = blockIdx.x * 256 + threadIdx.x;
  float bd = cd[n]; int bi = ci[n];
  #pragma unroll
  for (int g = 1; g < GROUPS; ++g) {
    float od = cd[g * N_TOK + n];
    int oi = ci[g * N_TOK + n];
    if (od < bd) { bd = od; bi = oi; }
  }
  idx[n] = bi;
  atomicAdd(enc + bi, 1.0f);
}

// ---------------------------------------------------------------------------
// K3: z_q gather + straight-through output + loss partials + embed_sum atomics.
__global__ void k_quant(const float* __restrict__ z, const float* __restrict__ weight,
                        const int* __restrict__ idx, float* __restrict__ out,
                        float* __restrict__ embed_acc, float* __restrict__ ws) {
  int base = blockIdx.x * 1024 + threadIdx.x;
  float lsum = 0.f;
  #pragma unroll
  for (int i = 0; i < 4; ++i) {
    int e = base + i * 256;               // (b,c,hw) flat, same layout as z
    int c = (e >> 10) & 63;
    int n = ((e >> 16) << 10) | (e & 1023);
    int k = idx[n];
    float zv = z[e];
    float q = weight[k * EMB_D + c];
    out[e] = zv + (q - zv);               // straight-through value
    float d = q - zv;
    lsum += d * d;
    atomicAdd(embed_acc + k * EMB_D + c, zv);
  }
  #pragma unroll
  for (int off = 32; off > 0; off >>= 1) lsum += __shfl_xor(lsum, off, 64);
  __shared__ float red[4];
  int lane = threadIdx.x & 63, wv = threadIdx.x >> 6;
  if (lane == 0) red[wv] = lsum;
  __syncthreads();
  if (threadIdx.x == 0)
    atomicAdd(ws + WS_LOSS, red[0] + red[1] + red[2] + red[3]);
}

// ---------------------------------------------------------------------------
// K4: new_cluster_size (in place over enc_sum), n-sum, loss finalize.
__global__ void k_cluster(const float* __restrict__ cluster_in,
                          float* __restrict__ out, float* __restrict__ ws) {
  int k = blockIdx.x * 256 + threadIdx.x;
  float ncs = cluster_in[k] * 0.99f + 0.01f * out[OFF_CS + k];
  out[OFF_CS + k] = ncs;
  float s = ncs;
  #pragma unroll
  for (int off = 32; off > 0; off >>= 1) s += __shfl_xor(s, off, 64);
  __shared__ float red[4];
  int lane = threadIdx.x & 63, wv = threadIdx.x >> 6;
  if (lane == 0) red[wv] = s;
  __syncthreads();
  if (threadIdx.x == 0) atomicAdd(ws + WS_NSUM, red[0] + red[1] + red[2] + red[3]);
  if (blockIdx.x == 0 && threadIdx.x == 0)
    out[OFF_LOSS] = 0.25f * ws[WS_LOSS] * (1.0f / 1048576.0f);
}

// ---------------------------------------------------------------------------
// K5: smoothed cluster sizes -> new_weight; new_embed_avg (in place).
__global__ void k_final(const float* __restrict__ embed_avg,
                        float* __restrict__ out, const float* __restrict__ ws) {
  int e = blockIdx.x * 256 + threadIdx.x;   // < 524288
  int k = e >> 6;
  float ncs = out[OFF_CS + k];
  float nsum = ws[WS_NSUM];
  float sm = (ncs + 1e-5f) / (nsum + K_EMB * 1e-5f) * nsum;
  float ea = embed_avg[e] * 0.99f + 0.01f * out[OFF_EA + e];
  out[OFF_EA + e] = ea;
  out[OFF_W + e] = ea / sm;
}

// ---------------------------------------------------------------------------
extern "C" void kernel_launch(void* const* d_in, const int* in_sizes, int n_in,
                              void* d_out, int out_size, void* d_ws, size_t ws_size,
                              hipStream_t stream) {
  const float* z = (const float*)d_in[0];
  const float* weight = (const float*)d_in[1];
  const float* cluster = (const float*)d_in[2];
  const float* embed_avg = (const float*)d_in[3];
  float* out = (float*)d_out;
  float* ws = (float*)d_ws;
  float* wnorm = ws + WS_WNORM;
  int* idx = (int*)(ws + WS_IDX);
  float* wt = out + OUT_WT;               // scratch in z_q region
  float* cd = out + OUT_CD;
  int* ci = (int*)(out + OUT_CI);

  hipLaunchKernelGGL(k_prep, dim3(512), dim3(256), 0, stream, weight, out, ws);
  hipLaunchKernelGGL(k_argmin, dim3(N_TOK / TN, GROUPS), dim3(256), 0, stream,
                     z, wt, wnorm, cd, ci);
  hipLaunchKernelGGL(k_reduce, dim3(N_TOK / 256), dim3(256), 0, stream,
                     cd, ci, idx, out + OFF_CS);
  hipLaunchKernelGGL(k_quant, dim3(1024), dim3(256), 0, stream,
                     z, weight, idx, out, out + OFF_EA, ws);
  hipLaunchKernelGGL(k_cluster, dim3(K_EMB / 256), dim3(256), 0, stream,
                     cluster, out, ws);
  hipLaunchKernelGGL(k_final, dim3(524288 / 256), dim3(256), 0, stream,
                     embed_avg, out, ws);
}

// Round 4
// 455.291 us; speedup vs baseline: 1.3173x; 1.0133x over previous
//
#include <hip/hip_runtime.h>

// EMA Vector-Quantizer for MI355X (gfx950).
// N=16384 tokens, D=64, K=8192. Dominant cost: 16384x8192x64 fp32 GEMM for
// distance argmin (no fp32 MFMA on CDNA4 -> VALU, 109 us FMA floor).
// R3: w read from pre-transposed w_t[d][k] in global (L2-resident); LDS holds
// only z (broadcast reads); single barrier; GROUPS=8 -> 1024 blocks.
// R4: __launch_bounds__(256,2) — the (256,4) bound in R3 forced VGPR_Count=64
// and spilled acc[8][8] to scratch (131 MB of HBM writes per dispatch!).
// (256,2) empirically allocates ~88-120 VGPR (R1/R2), no spill, and <=128
// still allows 4 blocks/CU from the actual allocation.

#define N_TOK 16384
#define K_EMB 8192
#define EMB_D 64
#define TN 128
#define GROUPS 8
#define KPG (K_EMB / GROUPS)   // 1024 codes per k-group, 8 kb-tiles of 128

// d_out flat layout (float32), in reference return order:
// z_q (1048576) | loss | new_weight (524288) | new_cluster_size (8192) | new_embed_avg (524288)
#define OFF_LOSS 1048576
#define OFF_W    1048577
#define OFF_CS   1572865
#define OFF_EA   1581057

// scratch inside the z_q region of out (all < 1048576, overwritten by k_quant)
#define OUT_WT 0                        // w_t[d][k]: 64 x 8192 = 524288 floats
#define OUT_CD 524288                   // cand dist [GROUPS][N_TOK] = 131072
#define OUT_CI (524288 + 131072)        // cand idx  [GROUPS][N_TOK] = 131072

// ws float offsets
#define WS_NSUM  0
#define WS_LOSS  1
#define WS_WNORM 16
#define WS_IDX   (WS_WNORM + K_EMB)

// ---------------------------------------------------------------------------
// K0: wnorm[k]; transpose weight -> w_t[d][k] (in out); zero accumulators.
__global__ void k_prep(const float* __restrict__ weight,
                       float* __restrict__ out, float* __restrict__ ws) {
  int gid = blockIdx.x * 256 + threadIdx.x;     // 0..131071
  int row = gid >> 4;                            // codebook row 0..8191
  int l16 = gid & 15;
  float4 w4 = *(const float4*)(weight + row * EMB_D + l16 * 4);
  float s = w4.x * w4.x + w4.y * w4.y + w4.z * w4.z + w4.w * w4.w;
  #pragma unroll
  for (int off = 8; off > 0; off >>= 1) s += __shfl_xor(s, off, 16);
  if (l16 == 0) ws[WS_WNORM + row] = s;

  // transposed copy: w_t[d*8192 + row], d = l16*4+c
  out[OUT_WT + (l16 * 4 + 0) * K_EMB + row] = w4.x;
  out[OUT_WT + (l16 * 4 + 1) * K_EMB + row] = w4.y;
  out[OUT_WT + (l16 * 4 + 2) * K_EMB + row] = w4.z;
  out[OUT_WT + (l16 * 4 + 3) * K_EMB + row] = w4.w;

  #pragma unroll
  for (int j = 0; j < 4; ++j) out[OFF_EA + gid * 4 + j] = 0.f;
  if (gid < K_EMB) out[OFF_CS + gid] = 0.f;
  if (gid == 0) { out[OFF_LOSS] = 0.f; ws[WS_NSUM] = 0.f; ws[WS_LOSS] = 0.f; }
}

// ---------------------------------------------------------------------------
// K1: distance argmin. Block: 128 n x 1024 k; thread tile 8n x 8k.
// grid (128, 8) x 256 threads. LDS 32KB; target 4 blocks/CU (16 waves).
// w fragment: k = ktb + g*64 + tx*4 + j -> contiguous dwordx4 from w_t rows.
// z fragment: LDS broadcast (4 distinct addresses per wave-read).
__global__ __launch_bounds__(256, 2) void k_argmin(
    const float* __restrict__ z, const float* __restrict__ wt,
    const float* __restrict__ wnorm, float* __restrict__ cd,
    int* __restrict__ ci) {
  __shared__ __align__(16) float z_s[EMB_D * TN];  // [d][n], 32 KB
  const int t = threadIdx.x;
  const int n0 = blockIdx.x * TN;
  const int kbase = blockIdx.y * KPG;
  // z is (b, c, hw): z_flat[n][d] = z[b*65536 + d*1024 + hw], n = b*1024+hw.
  const float* zb = z + ((n0 >> 10) << 16) + (n0 & 1023);

  #pragma unroll
  for (int i = 0; i < 8; ++i) {
    int f4 = i * 256 + t;                 // 0..2047 float4s
    int d = f4 >> 5, c4 = (f4 & 31) * 4;
    *(float4*)(z_s + d * TN + c4) = *(const float4*)(zb + d * 1024 + c4);
  }
  __syncthreads();                        // the only barrier

  const int tx = t & 15, ty = t >> 4;     // tx -> k, ty -> n
  float bestd[8];
  int besti[8];
  #pragma unroll
  for (int i = 0; i < 8; ++i) { bestd[i] = 3.4e38f; besti[i] = 0; }

  for (int kb = 0; kb < KPG / 128; ++kb) {
    const int ktb = kbase + kb * 128;
    float4 wn0 = *(const float4*)(wnorm + ktb + tx * 4);
    float4 wn1 = *(const float4*)(wnorm + ktb + 64 + tx * 4);

    float acc[8][8];
    #pragma unroll
    for (int i = 0; i < 8; ++i)
      #pragma unroll
      for (int j = 0; j < 8; ++j) acc[i][j] = 0.f;

    const float* wp = wt + ktb + tx * 4;  // row stride K_EMB per d
    #pragma unroll 4
    for (int d = 0; d < EMB_D; ++d) {
      float4 z0 = *(const float4*)(z_s + d * TN + ty * 8);
      float4 z1 = *(const float4*)(z_s + d * TN + ty * 8 + 4);
      float4 w0 = *(const float4*)(wp);
      float4 w1 = *(const float4*)(wp + 64);
      wp += K_EMB;
      float zr[8] = {z0.x, z0.y, z0.z, z0.w, z1.x, z1.y, z1.z, z1.w};
      float wr[8] = {w0.x, w0.y, w0.z, w0.w, w1.x, w1.y, w1.z, w1.w};
      #pragma unroll
      for (int i = 0; i < 8; ++i)
        #pragma unroll
        for (int j = 0; j < 8; ++j)
          acc[i][j] = fmaf(zr[i], wr[j], acc[i][j]);
    }

    // dist = |w|^2 - 2*dot. Per-thread k ascends over (g, j) -> strict <
    // keeps first-min; cross-thread ties resolved by index compare below.
    float wna[8] = {wn0.x, wn0.y, wn0.z, wn0.w, wn1.x, wn1.y, wn1.z, wn1.w};
    #pragma unroll
    for (int g = 0; g < 2; ++g)
      #pragma unroll
      for (int j = 0; j < 4; ++j) {
        int col = g * 4 + j;
        int kg = ktb + g * 64 + tx * 4 + j;
        float wn = wna[col];
        #pragma unroll
        for (int i = 0; i < 8; ++i) {
          float dist = fmaf(-2.f, acc[i][col], wn);
          if (dist < bestd[i]) { bestd[i] = dist; besti[i] = kg; }
        }
      }
  }

  // Reduce across the 16 tx threads sharing each n (same wave, width 16).
  #pragma unroll
  for (int i = 0; i < 8; ++i) {
    float bd = bestd[i]; int bi = besti[i];
    #pragma unroll
    for (int off = 8; off > 0; off >>= 1) {
      float od = __shfl_xor(bd, off, 16);
      int oi = __shfl_xor(bi, off, 16);
      if (od < bd || (od == bd && oi < bi)) { bd = od; bi = oi; }
    }
    if (tx == 0) {
      int n = n0 + ty * 8 + i;
      cd[blockIdx.y * N_TOK + n] = bd;
      ci[blockIdx.y * N_TOK + n] = bi;
    }
  }
}

// ---------------------------------------------------------------------------
// K2: reduce the GROUPS candidates per token; enc_sum atomics.
// Groups cover ascending k-ranges, so strict < keeps smallest index on tie.
__global__ void k_reduce(const float* __restrict__ cd, const int* __restrict__ ci,
                         int* __restrict__ idx, float* __restrict__ enc) {
  int n = blockIdx.x * 256 + threadIdx.x;
  float bd = cd[n]; int bi = ci[n];
  #pragma unroll
  for (int g = 1; g < GROUPS; ++g) {
    float od = cd[g * N_TOK + n];
    int oi = ci[g * N_TOK + n];
    if (od < bd) { bd = od; bi = oi; }
  }
  idx[n] = bi;
  atomicAdd(enc + bi, 1.0f);
}

// ---------------------------------------------------------------------------
// K3: z_q gather + straight-through output + loss partials + embed_sum atomics.
__global__ void k_quant(const float* __restrict__ z, const float* __restrict__ weight,
                        const int* __restrict__ idx, float* __restrict__ out,
                        float* __restrict__ embed_acc, float* __restrict__ ws) {
  int base = blockIdx.x * 1024 + threadIdx.x;
  float lsum = 0.f;
  #pragma unroll
  for (int i = 0; i < 4; ++i) {
    int e = base + i * 256;               // (b,c,hw) flat, same layout as z
    int c = (e >> 10) & 63;
    int n = ((e >> 16) << 10) | (e & 1023);
    int k = idx[n];
    float zv = z[e];
    float q = weight[k * EMB_D + c];
    out[e] = zv + (q - zv);               // straight-through value
    float d = q - zv;
    lsum += d * d;
    atomicAdd(embed_acc + k * EMB_D + c, zv);
  }
  #pragma unroll
  for (int off = 32; off > 0; off >>= 1) lsum += __shfl_xor(lsum, off, 64);
  __shared__ float red[4];
  int lane = threadIdx.x & 63, wv = threadIdx.x >> 6;
  if (lane == 0) red[wv] = lsum;
  __syncthreads();
  if (threadIdx.x == 0)
    atomicAdd(ws + WS_LOSS, red[0] + red[1] + red[2] + red[3]);
}

// ---------------------------------------------------------------------------
// K4: new_cluster_size (in place over enc_sum), n-sum, loss finalize.
__global__ void k_cluster(const float* __restrict__ cluster_in,
                          float* __restrict__ out, float* __restrict__ ws) {
  int k = blockIdx.x * 256 + threadIdx.x;
  float ncs = cluster_in[k] * 0.99f + 0.01f * out[OFF_CS + k];
  out[OFF_CS + k] = ncs;
  float s = ncs;
  #pragma unroll
  for (int off = 32; off > 0; off >>= 1) s += __shfl_xor(s, off, 64);
  __shared__ float red[4];
  int lane = threadIdx.x & 63, wv = threadIdx.x >> 6;
  if (lane == 0) red[wv] = s;
  __syncthreads();
  if (threadIdx.x == 0) atomicAdd(ws + WS_NSUM, red[0] + red[1] + red[2] + red[3]);
  if (blockIdx.x == 0 && threadIdx.x == 0)
    out[OFF_LOSS] = 0.25f * ws[WS_LOSS] * (1.0f / 1048576.0f);
}

// ---------------------------------------------------------------------------
// K5: smoothed cluster sizes -> new_weight; new_embed_avg (in place).
__global__ void k_final(const float* __restrict__ embed_avg,
                        float* __restrict__ out, const float* __restrict__ ws) {
  int e = blockIdx.x * 256 + threadIdx.x;   // < 524288
  int k = e >> 6;
  float ncs = out[OFF_CS + k];
  float nsum = ws[WS_NSUM];
  float sm = (ncs + 1e-5f) / (nsum + K_EMB * 1e-5f) * nsum;
  float ea = embed_avg[e] * 0.99f + 0.01f * out[OFF_EA + e];
  out[OFF_EA + e] = ea;
  out[OFF_W + e] = ea / sm;
}

// ---------------------------------------------------------------------------
extern "C" void kernel_launch(void* const* d_in, const int* in_sizes, int n_in,
                              void* d_out, int out_size, void* d_ws, size_t ws_size,
                              hipStream_t stream) {
  const float* z = (const float*)d_in[0];
  const float* weight = (const float*)d_in[1];
  const float* cluster = (const float*)d_in[2];
  const float* embed_avg = (const float*)d_in[3];
  float* out = (float*)d_out;
  float* ws = (float*)d_ws;
  float* wnorm = ws + WS_WNORM;
  int* idx = (int*)(ws + WS_IDX);
  float* wt = out + OUT_WT;               // scratch in z_q region
  float* cd = out + OUT_CD;
  int* ci = (int*)(out + OUT_CI);

  hipLaunchKernelGGL(k_prep, dim3(512), dim3(256), 0, stream, weight, out, ws);
  hipLaunchKernelGGL(k_argmin, dim3(N_TOK / TN, GROUPS), dim3(256), 0, stream,
                     z, wt, wnorm, cd, ci);
  hipLaunchKernelGGL(k_reduce, dim3(N_TOK / 256), dim3(256), 0, stream,
                     cd, ci, idx, out + OFF_CS);
  hipLaunchKernelGGL(k_quant, dim3(1024), dim3(256), 0, stream,
                     z, weight, idx, out, out + OFF_EA, ws);
  hipLaunchKernelGGL(k_cluster, dim3(K_EMB / 256), dim3(256), 0, stream,
                     cluster, out, ws);
  hipLaunchKernelGGL(k_final, dim3(524288 / 256), dim3(256), 0, stream,
                     embed_avg, out, ws);
}